// Round 19
// baseline (133.290 us; speedup 1.0000x reference)
//
#include <hip/hip_runtime.h>
#include <hip/hip_bf16.h>

#define NN 8192
#define KIN 512
#define KOUT 256
#define ALPHA 0.2f
#define BK 64
#define ROWS 128        // rows per block (k_attn)
#define KQ (NN / 4)     // k-range per quarter
#define NT4 (KQ / BK)   // 32 k-tiles per quarter

typedef __bf16 bf16x8 __attribute__((ext_vector_type(8)));
typedef float f32x4 __attribute__((ext_vector_type(4)));
typedef unsigned short ushort8_t __attribute__((ext_vector_type(8)));
typedef unsigned short ushort4_t __attribute__((ext_vector_type(4)));
typedef int int4v __attribute__((ext_vector_type(4)));

__device__ __forceinline__ float lrelu(float x) { return x > 0.f ? x : ALPHA * x; }

__device__ __forceinline__ unsigned short f2bf(float f) {
  union { float f; unsigned u; } v; v.f = f;
  unsigned r = v.u + 0x7fffu + ((v.u >> 16) & 1u);  // RNE to bf16
  return (unsigned short)(r >> 16);
}
__device__ __forceinline__ float bf2f(unsigned short b) {
  union { unsigned u; float f; } v; v.u = ((unsigned)b) << 16;
  return v.f;
}

// pack two f32 -> one u32 of 2x bf16 (RNE) via HW instruction
__device__ __forceinline__ unsigned cvt_pk_bf16(float lo, float hi) {
  unsigned r;
  asm("v_cvt_pk_bf16_f32 %0, %1, %2" : "=v"(r) : "v"(lo), "v"(hi));
  return r;
}

// monotone float->uint key for atomicMax
__device__ __forceinline__ unsigned fkey(float x) {
  unsigned b = __float_as_uint(x);
  return (b & 0x80000000u) ? ~b : (b | 0x80000000u);
}
__device__ __forceinline__ float funkey(unsigned k) {
  unsigned b = (k & 0x80000000u) ? (k ^ 0x80000000u) : ~k;
  return __uint_as_float(b);
}

#define MF(a, b, c) __builtin_amdgcn_mfma_f32_16x16x32_bf16(a, b, c, 0, 0, 0)

// ---- k_wp: merged prep. blocks 0..63: W -> Wb (frag order); 64,65: Wa1/Wa2 -
__global__ __launch_bounds__(256) void k_wp(const float* __restrict__ W,
                                            const float* __restrict__ a1,
                                            const float* __restrict__ a2,
                                            unsigned short* __restrict__ Wb,
                                            float* __restrict__ Wa1,
                                            float* __restrict__ Wa2,
                                            unsigned* __restrict__ Dup) {
  const int blk = blockIdx.x;
  const int tid = threadIdx.x;
  if (blk < 64) {
    const int b = blk * 4 + (tid >> 6);   // 0..255 = kt*16 + cg
    const int kt = b >> 4, cg = b & 15;
    const int l = tid & 63;
    const int krow = kt * 32 + (l >> 4) * 8;
    const int col = cg * 16 + (l & 15);
    ushort8_t o;
#pragma unroll
    for (int e = 0; e < 8; ++e) o[e] = f2bf(W[(size_t)(krow + e) * KOUT + col]);
    *(ushort8_t*)(Wb + ((size_t)b * 64 + l) * 8) = o;
  } else {
    const int k = (blk - 64) * 256 + tid;  // 0..511
    float s1 = 0.f, s2 = 0.f;
    const float* wr = W + (size_t)k * KOUT;
    for (int c = 0; c < KOUT; c += 4) {
      float4 w4 = *(const float4*)(wr + c);
      float4 b1 = *(const float4*)(a1 + c);
      float4 b2 = *(const float4*)(a2 + c);
      s1 += w4.x * b1.x + w4.y * b1.y + w4.z * b1.z + w4.w * b1.w;
      s2 += w4.x * b2.x + w4.y * b2.y + w4.z * b2.z + w4.w * b2.w;
    }
    Wa1[k] = s1;
    Wa2[k] = s2;
    if (k == 0) *Dup = 0u;  // key(x) > 0 for any real float
  }
}

// -------- k_wh2: Wh = h @ W via MFMA; writes WhF fragment-order direct -----
__global__ __launch_bounds__(512) void k_wh2(const float* __restrict__ h,
                                             const unsigned short* __restrict__ Wb,
                                             const float* __restrict__ Wa1,
                                             const float* __restrict__ Wa2,
                                             unsigned short* __restrict__ WhF,
                                             float* __restrict__ src,
                                             float* __restrict__ dstv,
                                             unsigned* __restrict__ Dup) {
  __shared__ unsigned short sH[64][64];        // 8 KB, XOR-swizzled rows
  __shared__ unsigned short sBounce[64][132];  // 16.5 KB epilogue bounce (padded)
  __shared__ float sW1[KIN], sW2[KIN];         // 4 KB
  char* sHb = (char*)&sH[0][0];
  const int tid = threadIdx.x;
  const int lane = tid & 63;
  const int wv = tid >> 6;       // 0..7
  const int kt = blockIdx.x;     // one 64-row k-tile per block
  const int r0 = kt * 64;
  const int fr = lane & 15, fq = lane >> 4;

  sW1[tid] = Wa1[tid];
  sW2[tid] = Wa2[tid];

  const int srow = tid >> 3;
  const int skc = (tid & 7) * 8;
  const float* hp = h + (size_t)(r0 + srow) * KIN + skc;
  const int wby = ((srow * 128 + skc * 2) ^ ((srow & 7) << 4));
  float sp = 0.f, dp = 0.f;

  f32x4 acc[4][2];
#pragma unroll
  for (int mr = 0; mr < 4; ++mr) {
    acc[mr][0] = (f32x4){0.f, 0.f, 0.f, 0.f};
    acc[mr][1] = (f32x4){0.f, 0.f, 0.f, 0.f};
  }
  ushort8_t Bs[2][2];  // [n][kk]

  float hv[8];
  {
    float4 a = *(const float4*)hp;
    float4 b = *(const float4*)(hp + 4);
    hv[0] = a.x; hv[1] = a.y; hv[2] = a.z; hv[3] = a.w;
    hv[4] = b.x; hv[5] = b.y; hv[6] = b.z; hv[7] = b.w;
  }

#pragma unroll 1
  for (int it = 0; it < 8; ++it) {
    __syncthreads();
    const int kb = it * 64 + skc;
#pragma unroll
    for (int j = 0; j < 8; ++j) {
      sp = fmaf(hv[j], sW1[kb + j], sp);
      dp = fmaf(hv[j], sW2[kb + j], dp);
    }
    uint4 pk;
    pk.x = cvt_pk_bf16(hv[0], hv[1]);
    pk.y = cvt_pk_bf16(hv[2], hv[3]);
    pk.z = cvt_pk_bf16(hv[4], hv[5]);
    pk.w = cvt_pk_bf16(hv[6], hv[7]);
    *(uint4*)(sHb + wby) = pk;
    float hn[8];
    if (it < 7) {
      float4 a = *(const float4*)(hp + (it + 1) * 64);
      float4 b = *(const float4*)(hp + (it + 1) * 64 + 4);
      hn[0] = a.x; hn[1] = a.y; hn[2] = a.z; hn[3] = a.w;
      hn[4] = b.x; hn[5] = b.y; hn[6] = b.z; hn[7] = b.w;
    }
    __syncthreads();
#pragma unroll
    for (int n = 0; n < 2; ++n)
#pragma unroll
      for (int kk = 0; kk < 2; ++kk)
        Bs[n][kk] = *(const ushort8_t*)(Wb +
            (((size_t)(it * 2 + kk) * 16 + wv * 2 + n) * 64 + lane) * 8);
#pragma unroll
    for (int mr = 0; mr < 4; ++mr) {
      bf16x8 a0 = __builtin_bit_cast(bf16x8, *(const ushort8_t*)(sHb +
          (((mr * 16 + fr) * 128 + 0 * 64 + fq * 16) ^ ((fr & 7) << 4))));
      bf16x8 a1 = __builtin_bit_cast(bf16x8, *(const ushort8_t*)(sHb +
          (((mr * 16 + fr) * 128 + 1 * 64 + fq * 16) ^ ((fr & 7) << 4))));
      acc[mr][0] = MF(a0, Bs[0][0], acc[mr][0]);
      acc[mr][0] = MF(a1, Bs[0][1], acc[mr][0]);
      acc[mr][1] = MF(a0, Bs[1][0], acc[mr][1]);
      acc[mr][1] = MF(a1, Bs[1][1], acc[mr][1]);
    }
#pragma unroll
    for (int j = 0; j < 8; ++j) hv[j] = hn[j];
  }

  sp += __shfl_xor(sp, 1, 8);
  sp += __shfl_xor(sp, 2, 8);
  sp += __shfl_xor(sp, 4, 8);
  dp += __shfl_xor(dp, 1, 8);
  dp += __shfl_xor(dp, 2, 8);
  dp += __shfl_xor(dp, 4, 8);
  if ((tid & 7) == 0) {
    src[r0 + srow] = sp;
    dstv[r0 + srow] = dp;
    atomicMax(Dup, fkey(dp));
  }

#pragma unroll 1
  for (int pass = 0; pass < 2; ++pass) {
    __syncthreads();
    if ((wv >> 2) == pass) {
      const int fbase = (wv & 3) * 32;
#pragma unroll
      for (int mr = 0; mr < 4; ++mr)
#pragma unroll
        for (int n = 0; n < 2; ++n)
#pragma unroll
          for (int r = 0; r < 4; ++r)
            sBounce[mr * 16 + fq * 4 + r][fbase + n * 16 + fr] =
                f2bf(acc[mr][n][r]);
    }
    __syncthreads();
#pragma unroll
    for (int i = 0; i < 2; ++i) {
      const int g = wv * 2 + i;          // 0..15
      const int wloc = g >> 2;           // 0..3
      const int nc = (g >> 1) & 1;
      const int kh = g & 1;
      ushort8_t o;
#pragma unroll
      for (int e = 0; e < 8; ++e)
        o[e] = sBounce[kh * 32 + (lane >> 4) * 8 + e][wloc * 32 + nc * 16 + (lane & 15)];
      const int w = pass * 4 + wloc;
      const size_t idx = ((((size_t)kt * 8 + w) * 2 + nc) * 2 + kh) * 64 + lane;
      *(ushort8_t*)(WhF + idx * 8) = o;
    }
  }
}

// ---- k_attn: R14 consumer + 4-slot adj slack (4-phase) producers ---------
struct Bset { ushort8_t b[2][2]; };  // [nc][kh]

#define BAR()                                              \
  {                                                        \
    asm volatile("s_waitcnt lgkmcnt(0)" ::: "memory");     \
    __builtin_amdgcn_s_barrier();                          \
    asm volatile("" ::: "memory");                         \
  }

#define TI(t) (((t) + ph0) & (NT4 - 1))

#define LOADB(BS, ktl)                                                 \
  {                                                                    \
    const unsigned short* p_ = bfw + (size_t)(ktl) * 16384;            \
    BS.b[0][0] = *(const ushort8_t*)(p_);                              \
    BS.b[0][1] = *(const ushort8_t*)(p_ + 512);                        \
    BS.b[1][0] = *(const ushort8_t*)(p_ + 1024);                       \
    BS.b[1][1] = *(const ushort8_t*)(p_ + 1536);                       \
  }

#define WGEN4(AJ, ktl, koff, buf)                                      \
  {                                                                    \
    float4 dv = *(const float4*)&sD[(ktl) * BK + (koff)];              \
    float x0 = s_r + dv.x, x1 = s_r + dv.y;                            \
    float x2 = s_r + dv.z, x3 = s_r + dv.w;                            \
    float w0 = (AJ.x > 0) ? __expf(fmaxf(x0, ALPHA * x0) - c_r) : 0.f; \
    float w1 = (AJ.y > 0) ? __expf(fmaxf(x1, ALPHA * x1) - c_r) : 0.f; \
    float w2 = (AJ.z > 0) ? __expf(fmaxf(x2, ALPHA * x2) - c_r) : 0.f; \
    float w3 = (AJ.w > 0) ? __expf(fmaxf(x3, ALPHA * x3) - c_r) : 0.f; \
    lsum += (w0 + w1) + (w2 + w3);                                     \
    uint2 pk;                                                          \
    pk.x = cvt_pk_bf16(w0, w1);                                        \
    pk.y = cvt_pk_bf16(w2, w3);                                        \
    *(uint2*)(sAb + (buf) * 16384 +                                    \
              ((pr * 128 + (koff) * 2) ^ ((pr & 7) << 4))) = pk;       \
  }

#define WGEN16(A0, A1, A2, A3, ktl, buf)                               \
  {                                                                    \
    WGEN4(A0, ktl, pk16 + 0, buf);                                     \
    WGEN4(A1, ktl, pk16 + 4, buf);                                     \
    WGEN4(A2, ktl, pk16 + 8, buf);                                     \
    WGEN4(A3, ktl, pk16 + 12, buf);                                    \
  }

#define LOADADJ16(A0, A1, A2, A3, ktl)                                 \
  {                                                                    \
    const int4v* ap = (const int4v*)(adjp + (size_t)(ktl) * BK);       \
    A0 = __builtin_nontemporal_load(ap);                               \
    A1 = __builtin_nontemporal_load(ap + 1);                           \
    A2 = __builtin_nontemporal_load(ap + 2);                           \
    A3 = __builtin_nontemporal_load(ap + 3);                           \
  }

#define LDA(cur, mr, kk)                                                        \
  __builtin_bit_cast(bf16x8,                                                    \
    *(const ushort8_t*)(sAb + (cur) * 16384 +                                   \
      ((((mr) * 16 + fr) * 128 + (kk) * 64 + fq * 16) ^ ((fr & 7) << 4))))

#define MSTEP(cur, BS)                                                 \
  {                                                                    \
    _Pragma("unroll")                                                  \
    for (int mr = 0; mr < 8; ++mr) {                                   \
      bf16x8 a0 = LDA(cur, mr, 0), a1 = LDA(cur, mr, 1);               \
      acc[mr][0] = MF(a0, BS.b[0][0], acc[mr][0]);                     \
      acc[mr][0] = MF(a1, BS.b[0][1], acc[mr][0]);                     \
      acc[mr][1] = MF(a0, BS.b[1][0], acc[mr][1]);                     \
      acc[mr][1] = MF(a1, BS.b[1][1], acc[mr][1]);                     \
    }                                                                  \
  }

__global__ __launch_bounds__(1024) void k_attn(const int* __restrict__ adj,
                                               const unsigned short* __restrict__ WhF,
                                               const float* __restrict__ src,
                                               const float* __restrict__ dstv,
                                               const unsigned* __restrict__ Dup,
                                               unsigned short* __restrict__ Pb16,
                                               float* __restrict__ Lsum) {
  __shared__ unsigned short sA[2][ROWS][BK];  // 32 KB dbuf, XOR-swizzled rows
  __shared__ float sD[KQ];                    // 8 KB: this quarter's dstv
  char* sAb = (char*)&sA[0][0][0];
  const int tid = threadIdx.x;
  const int lane = tid & 63;
  const int wave = tid >> 6;      // 0..7 consumers, 8..15 producers
  const int qtr = blockIdx.x & 3;
  const int rg = blockIdx.x >> 2;
  const int r0 = rg * ROWS;
  const int ph0 = rg & (NT4 - 1);
  const int kbase = qtr * KQ;
  const float D = funkey(*Dup);

  *(float2*)&sD[tid * 2] = *(const float2*)(dstv + kbase + tid * 2);
  __syncthreads();

  // ---------- producer state (waves 8..15): 4 threads per row ----------
  const int ptid = tid - 512;
  const int pr = ptid >> 2;
  const int pk16 = (ptid & 3) * 16;
  const float s_r = src[r0 + pr];
  const float c_r = lrelu(s_r + D);
  const int* adjp = adj + (size_t)(r0 + pr) * NN + kbase + pk16;
  float lsum = 0.f;

  // ---------- consumer state (waves 0..7): wave tile 128x32 ----------
  const int fr = lane & 15;
  const int fq = lane >> 4;
  const unsigned short* bfw =
      WhF + ((size_t)(qtr * NT4) * 8 + wave) * 2048 + lane * 8;
  f32x4 acc[8][2];
#pragma unroll
  for (int mr = 0; mr < 8; ++mr) {
    acc[mr][0] = (f32x4){0.f, 0.f, 0.f, 0.f};
    acc[mr][1] = (f32x4){0.f, 0.f, 0.f, 0.f};
  }
  Bset B0, B1;
  // 4 adj slot-sets: slot s holds tile consumed at phase p where (p mod 4)==s
  int4v s1a, s1b, s1c, s1d;   // tiles 1,5,9,...  (phase p%4==0, buf1)
  int4v s2a, s2b, s2c, s2d;   // tiles 2,6,10,... (phase p%4==1, buf0)
  int4v s3a, s3b, s3c, s3d;   // tiles 3,7,11,... (phase p%4==2, buf1)
  int4v s0a, s0b, s0c, s0d;   // tiles 4,8,12,... (phase p%4==3, buf0)

  // ---------- prologue ----------
  if (wave >= 8) {
    int4v d0, d1, d2, d3;
    {
      const int4v* ap = (const int4v*)(adjp + (size_t)TI(0) * BK);
      d0 = ap[0]; d1 = ap[1]; d2 = ap[2]; d3 = ap[3];
    }
    WGEN16(d0, d1, d2, d3, TI(0), 0);
    LOADADJ16(s1a, s1b, s1c, s1d, TI(1));
    LOADADJ16(s2a, s2b, s2c, s2d, TI(2));
    LOADADJ16(s3a, s3b, s3c, s3d, TI(3));
    LOADADJ16(s0a, s0b, s0c, s0d, TI(4));
  } else {
    LOADB(B0, TI(0));
    LOADB(B1, TI(1));
  }
  BAR();

  // ---------- main loop ----------
  if (wave < 8) {
#pragma unroll 1
    for (int p = 0; p < NT4; p += 2) {
      { MSTEP(0, B0); LOADB(B0, TI(p + 2)); BAR(); }
      { MSTEP(1, B1); LOADB(B1, TI(p + 3)); BAR(); }
    }
    // store bf16 partial accumulators
#pragma unroll
    for (int mr = 0; mr < 8; ++mr) {
#pragma unroll
      for (int r = 0; r < 4; ++r) {
        const int row = mr * 16 + fq * 4 + r;
#pragma unroll
        for (int nc = 0; nc < 2; ++nc) {
          const int col = wave * 32 + nc * 16 + fr;
          Pb16[(size_t)(qtr * NN + r0 + row) * KOUT + col] = f2bf(acc[mr][nc][r]);
        }
      }
    }
  } else {
    // producer: 4 phases per iteration, 4-phase adj slack
#pragma unroll 1
    for (int p = 0; p < NT4; p += 4) {
      {  // phase p: tile p+1 -> buf1
        WGEN16(s1a, s1b, s1c, s1d, TI(p + 1), 1);
        LOADADJ16(s1a, s1b, s1c, s1d, TI(p + 5));
        BAR();
      }
      {  // phase p+1: tile p+2 -> buf0
        WGEN16(s2a, s2b, s2c, s2d, TI(p + 2), 0);
        LOADADJ16(s2a, s2b, s2c, s2d, TI(p + 6));
        BAR();
      }
      {  // phase p+2: tile p+3 -> buf1
        WGEN16(s3a, s3b, s3c, s3d, TI(p + 3), 1);
        LOADADJ16(s3a, s3b, s3c, s3d, TI(p + 7));
        BAR();
      }
      {  // phase p+3: tile p+4 -> buf0 (guarded: last iteration has no tile 32)
        if (p + 4 < NT4) { WGEN16(s0a, s0b, s0c, s0d, TI(p + 4), 0); }
        LOADADJ16(s0a, s0b, s0c, s0d, TI(p + 8));
        BAR();
      }
    }
    lsum += __shfl_xor(lsum, 1, 4);
    lsum += __shfl_xor(lsum, 2, 4);
    if ((ptid & 3) == 0) Lsum[qtr * NN + r0 + pr] = lsum;
  }
}

// ---------------- k_comb: out = elu(sum(P)/sum(L)) -----------------------
__global__ __launch_bounds__(256) void k_comb(const unsigned short* __restrict__ Pb16,
                                              const float* __restrict__ Lsum,
                                              float* __restrict__ out) {
  const int t = threadIdx.x;
  const int row = blockIdx.x * 4 + (t >> 6);
  const int col = (t & 63) * 4;
  const float l = Lsum[row] + Lsum[NN + row] + Lsum[2 * NN + row] + Lsum[3 * NN + row];
  float s0 = 0.f, s1 = 0.f, s2 = 0.f, s3 = 0.f;
#pragma unroll
  for (int q = 0; q < 4; ++q) {
    ushort4_t p = *(const ushort4_t*)(Pb16 + (size_t)(q * NN + row) * KOUT + col);
    s0 += bf2f(p[0]);
    s1 += bf2f(p[1]);
    s2 += bf2f(p[2]);
    s3 += bf2f(p[3]);
  }
  float4 v;
  v.x = s0 / l;
  v.y = s1 / l;
  v.z = s2 / l;
  v.w = s3 / l;
  v.x = v.x > 0.f ? v.x : __expf(v.x) - 1.f;
  v.y = v.y > 0.f ? v.y : __expf(v.y) - 1.f;
  v.z = v.z > 0.f ? v.z : __expf(v.z) - 1.f;
  v.w = v.w > 0.f ? v.w : __expf(v.w) - 1.f;
  *(float4*)(out + (size_t)row * KOUT + col) = v;
}

extern "C" void kernel_launch(void* const* d_in, const int* in_sizes, int n_in,
                              void* d_out, int out_size, void* d_ws, size_t ws_size,
                              hipStream_t stream) {
  const float* h = (const float*)d_in[0];
  const int* adj = (const int*)d_in[1];
  const float* W = (const float*)d_in[2];
  const float* a1 = (const float*)d_in[3];
  const float* a2 = (const float*)d_in[4];
  float* out = (float*)d_out;

  unsigned short* WhF = (unsigned short*)d_ws;            // 4 MB (fragment order)
  float* src = (float*)(WhF + (size_t)NN * KOUT);         // 32 KB
  float* dstv = src + NN;                                 // 32 KB
  unsigned* Dup = (unsigned*)(dstv + NN);                 // pad 16
  unsigned short* Pb16 = (unsigned short*)(Dup + 16);     // 16 MB bf16 partials
  float* Lsum = (float*)(Pb16 + (size_t)4 * NN * KOUT);   // 128 KB
  unsigned short* Wb = (unsigned short*)(Lsum + 4 * NN);  // 256 KB frag W
  float* Wa1 = (float*)(Wb + (size_t)KIN * KOUT);         // 2 KB
  float* Wa2 = Wa1 + KIN;                                 // 2 KB

  hipLaunchKernelGGL(k_wp, dim3(66), dim3(256), 0, stream, W, a1, a2, Wb, Wa1, Wa2, Dup);
  hipLaunchKernelGGL(k_wh2, dim3(NN / 64), dim3(512), 0, stream,
                     h, Wb, Wa1, Wa2, WhF, src, dstv, Dup);
  hipLaunchKernelGGL(k_attn, dim3(256), dim3(1024), 0, stream,
                     adj, WhF, src, dstv, Dup, Pb16, Lsum);
  hipLaunchKernelGGL(k_comb, dim3(NN / 4), dim3(256), 0, stream, Pb16, Lsum, out);
}

// Round 20
// 128.116 us; speedup vs baseline: 1.0404x; 1.0404x over previous
//
#include <hip/hip_runtime.h>
#include <hip/hip_bf16.h>

#define NN 8192
#define KIN 512
#define KOUT 256
#define ALPHA 0.2f
#define BK 64
#define ROWS 128        // rows per block (k_attn)
#define KQ (NN / 4)     // k-range per quarter
#define NT4 (KQ / BK)   // 32 k-tiles per quarter

typedef __bf16 bf16x8 __attribute__((ext_vector_type(8)));
typedef float f32x4 __attribute__((ext_vector_type(4)));
typedef unsigned short ushort8_t __attribute__((ext_vector_type(8)));
typedef unsigned short ushort4_t __attribute__((ext_vector_type(4)));
typedef int int4v __attribute__((ext_vector_type(4)));

__device__ __forceinline__ float lrelu(float x) { return x > 0.f ? x : ALPHA * x; }

__device__ __forceinline__ unsigned short f2bf(float f) {
  union { float f; unsigned u; } v; v.f = f;
  unsigned r = v.u + 0x7fffu + ((v.u >> 16) & 1u);  // RNE to bf16
  return (unsigned short)(r >> 16);
}
__device__ __forceinline__ float bf2f(unsigned short b) {
  union { unsigned u; float f; } v; v.u = ((unsigned)b) << 16;
  return v.f;
}

// pack two f32 -> one u32 of 2x bf16 (RNE) via HW instruction
__device__ __forceinline__ unsigned cvt_pk_bf16(float lo, float hi) {
  unsigned r;
  asm("v_cvt_pk_bf16_f32 %0, %1, %2" : "=v"(r) : "v"(lo), "v"(hi));
  return r;
}

// monotone float->uint key for atomicMax
__device__ __forceinline__ unsigned fkey(float x) {
  unsigned b = __float_as_uint(x);
  return (b & 0x80000000u) ? ~b : (b | 0x80000000u);
}
__device__ __forceinline__ float funkey(unsigned k) {
  unsigned b = (k & 0x80000000u) ? (k ^ 0x80000000u) : ~k;
  return __uint_as_float(b);
}

#define MF(a, b, c) __builtin_amdgcn_mfma_f32_16x16x32_bf16(a, b, c, 0, 0, 0)

// ---- k_wp: merged prep. blocks 0..63: W -> Wb (frag order); 64,65: Wa1/Wa2 -
__global__ __launch_bounds__(256) void k_wp(const float* __restrict__ W,
                                            const float* __restrict__ a1,
                                            const float* __restrict__ a2,
                                            unsigned short* __restrict__ Wb,
                                            float* __restrict__ Wa1,
                                            float* __restrict__ Wa2,
                                            unsigned* __restrict__ Dup) {
  const int blk = blockIdx.x;
  const int tid = threadIdx.x;
  if (blk < 64) {
    const int b = blk * 4 + (tid >> 6);   // 0..255 = kt*16 + cg
    const int kt = b >> 4, cg = b & 15;
    const int l = tid & 63;
    const int krow = kt * 32 + (l >> 4) * 8;
    const int col = cg * 16 + (l & 15);
    ushort8_t o;
#pragma unroll
    for (int e = 0; e < 8; ++e) o[e] = f2bf(W[(size_t)(krow + e) * KOUT + col]);
    *(ushort8_t*)(Wb + ((size_t)b * 64 + l) * 8) = o;
  } else {
    const int k = (blk - 64) * 256 + tid;  // 0..511
    float s1 = 0.f, s2 = 0.f;
    const float* wr = W + (size_t)k * KOUT;
    for (int c = 0; c < KOUT; c += 4) {
      float4 w4 = *(const float4*)(wr + c);
      float4 b1 = *(const float4*)(a1 + c);
      float4 b2 = *(const float4*)(a2 + c);
      s1 += w4.x * b1.x + w4.y * b1.y + w4.z * b1.z + w4.w * b1.w;
      s2 += w4.x * b2.x + w4.y * b2.y + w4.z * b2.z + w4.w * b2.w;
    }
    Wa1[k] = s1;
    Wa2[k] = s2;
    if (k == 0) *Dup = 0u;  // key(x) > 0 for any real float
  }
}

// -------- k_wh2: Wh = h @ W via MFMA; writes WhF fragment-order direct -----
__global__ __launch_bounds__(512) void k_wh2(const float* __restrict__ h,
                                             const unsigned short* __restrict__ Wb,
                                             const float* __restrict__ Wa1,
                                             const float* __restrict__ Wa2,
                                             unsigned short* __restrict__ WhF,
                                             float* __restrict__ src,
                                             float* __restrict__ dstv,
                                             unsigned* __restrict__ Dup) {
  __shared__ unsigned short sH[64][64];        // 8 KB, XOR-swizzled rows
  __shared__ unsigned short sBounce[64][132];  // 16.5 KB epilogue bounce (padded)
  __shared__ float sW1[KIN], sW2[KIN];         // 4 KB
  char* sHb = (char*)&sH[0][0];
  const int tid = threadIdx.x;
  const int lane = tid & 63;
  const int wv = tid >> 6;       // 0..7
  const int kt = blockIdx.x;     // one 64-row k-tile per block
  const int r0 = kt * 64;
  const int fr = lane & 15, fq = lane >> 4;

  sW1[tid] = Wa1[tid];
  sW2[tid] = Wa2[tid];

  const int srow = tid >> 3;
  const int skc = (tid & 7) * 8;
  const float* hp = h + (size_t)(r0 + srow) * KIN + skc;
  const int wby = ((srow * 128 + skc * 2) ^ ((srow & 7) << 4));
  float sp = 0.f, dp = 0.f;

  f32x4 acc[4][2];
#pragma unroll
  for (int mr = 0; mr < 4; ++mr) {
    acc[mr][0] = (f32x4){0.f, 0.f, 0.f, 0.f};
    acc[mr][1] = (f32x4){0.f, 0.f, 0.f, 0.f};
  }
  ushort8_t Bs[2][2];  // [n][kk]

  float hv[8];
  {
    float4 a = *(const float4*)hp;
    float4 b = *(const float4*)(hp + 4);
    hv[0] = a.x; hv[1] = a.y; hv[2] = a.z; hv[3] = a.w;
    hv[4] = b.x; hv[5] = b.y; hv[6] = b.z; hv[7] = b.w;
  }

#pragma unroll 1
  for (int it = 0; it < 8; ++it) {
    __syncthreads();
    const int kb = it * 64 + skc;
#pragma unroll
    for (int j = 0; j < 8; ++j) {
      sp = fmaf(hv[j], sW1[kb + j], sp);
      dp = fmaf(hv[j], sW2[kb + j], dp);
    }
    uint4 pk;
    pk.x = cvt_pk_bf16(hv[0], hv[1]);
    pk.y = cvt_pk_bf16(hv[2], hv[3]);
    pk.z = cvt_pk_bf16(hv[4], hv[5]);
    pk.w = cvt_pk_bf16(hv[6], hv[7]);
    *(uint4*)(sHb + wby) = pk;
    float hn[8];
    if (it < 7) {
      float4 a = *(const float4*)(hp + (it + 1) * 64);
      float4 b = *(const float4*)(hp + (it + 1) * 64 + 4);
      hn[0] = a.x; hn[1] = a.y; hn[2] = a.z; hn[3] = a.w;
      hn[4] = b.x; hn[5] = b.y; hn[6] = b.z; hn[7] = b.w;
    }
    __syncthreads();
#pragma unroll
    for (int n = 0; n < 2; ++n)
#pragma unroll
      for (int kk = 0; kk < 2; ++kk)
        Bs[n][kk] = *(const ushort8_t*)(Wb +
            (((size_t)(it * 2 + kk) * 16 + wv * 2 + n) * 64 + lane) * 8);
#pragma unroll
    for (int mr = 0; mr < 4; ++mr) {
      bf16x8 a0 = __builtin_bit_cast(bf16x8, *(const ushort8_t*)(sHb +
          (((mr * 16 + fr) * 128 + 0 * 64 + fq * 16) ^ ((fr & 7) << 4))));
      bf16x8 a1 = __builtin_bit_cast(bf16x8, *(const ushort8_t*)(sHb +
          (((mr * 16 + fr) * 128 + 1 * 64 + fq * 16) ^ ((fr & 7) << 4))));
      acc[mr][0] = MF(a0, Bs[0][0], acc[mr][0]);
      acc[mr][0] = MF(a1, Bs[0][1], acc[mr][0]);
      acc[mr][1] = MF(a0, Bs[1][0], acc[mr][1]);
      acc[mr][1] = MF(a1, Bs[1][1], acc[mr][1]);
    }
#pragma unroll
    for (int j = 0; j < 8; ++j) hv[j] = hn[j];
  }

  sp += __shfl_xor(sp, 1, 8);
  sp += __shfl_xor(sp, 2, 8);
  sp += __shfl_xor(sp, 4, 8);
  dp += __shfl_xor(dp, 1, 8);
  dp += __shfl_xor(dp, 2, 8);
  dp += __shfl_xor(dp, 4, 8);
  if ((tid & 7) == 0) {
    src[r0 + srow] = sp;
    dstv[r0 + srow] = dp;
    atomicMax(Dup, fkey(dp));
  }

#pragma unroll 1
  for (int pass = 0; pass < 2; ++pass) {
    __syncthreads();
    if ((wv >> 2) == pass) {
      const int fbase = (wv & 3) * 32;
#pragma unroll
      for (int mr = 0; mr < 4; ++mr)
#pragma unroll
        for (int n = 0; n < 2; ++n)
#pragma unroll
          for (int r = 0; r < 4; ++r)
            sBounce[mr * 16 + fq * 4 + r][fbase + n * 16 + fr] =
                f2bf(acc[mr][n][r]);
    }
    __syncthreads();
#pragma unroll
    for (int i = 0; i < 2; ++i) {
      const int g = wv * 2 + i;          // 0..15
      const int wloc = g >> 2;           // 0..3
      const int nc = (g >> 1) & 1;
      const int kh = g & 1;
      ushort8_t o;
#pragma unroll
      for (int e = 0; e < 8; ++e)
        o[e] = sBounce[kh * 32 + (lane >> 4) * 8 + e][wloc * 32 + nc * 16 + (lane & 15)];
      const int w = pass * 4 + wloc;
      const size_t idx = ((((size_t)kt * 8 + w) * 2 + nc) * 2 + kh) * 64 + lane;
      *(ushort8_t*)(WhF + idx * 8) = o;
    }
  }
}

// ---- k_attn: R14 optimum (2-slot B, 128x32 consumer tiles, lean prods) ---
struct Bset { ushort8_t b[2][2]; };  // [nc][kh]

#define BAR()                                              \
  {                                                        \
    asm volatile("s_waitcnt lgkmcnt(0)" ::: "memory");     \
    __builtin_amdgcn_s_barrier();                          \
    asm volatile("" ::: "memory");                         \
  }

#define TI(t) (((t) + ph0) & (NT4 - 1))

#define LOADB(BS, ktl)                                                 \
  {                                                                    \
    const unsigned short* p_ = bfw + (size_t)(ktl) * 16384;            \
    BS.b[0][0] = *(const ushort8_t*)(p_);                              \
    BS.b[0][1] = *(const ushort8_t*)(p_ + 512);                        \
    BS.b[1][0] = *(const ushort8_t*)(p_ + 1024);                       \
    BS.b[1][1] = *(const ushort8_t*)(p_ + 1536);                       \
  }

#define WGEN4(AJ, ktl, koff, buf)                                      \
  {                                                                    \
    float4 dv = *(const float4*)&sD[(ktl) * BK + (koff)];              \
    float x0 = s_r + dv.x, x1 = s_r + dv.y;                            \
    float x2 = s_r + dv.z, x3 = s_r + dv.w;                            \
    float w0 = (AJ.x > 0) ? __expf(fmaxf(x0, ALPHA * x0) - c_r) : 0.f; \
    float w1 = (AJ.y > 0) ? __expf(fmaxf(x1, ALPHA * x1) - c_r) : 0.f; \
    float w2 = (AJ.z > 0) ? __expf(fmaxf(x2, ALPHA * x2) - c_r) : 0.f; \
    float w3 = (AJ.w > 0) ? __expf(fmaxf(x3, ALPHA * x3) - c_r) : 0.f; \
    lsum += (w0 + w1) + (w2 + w3);                                     \
    uint2 pk;                                                          \
    pk.x = cvt_pk_bf16(w0, w1);                                        \
    pk.y = cvt_pk_bf16(w2, w3);                                        \
    *(uint2*)(sAb + (buf) * 16384 +                                    \
              ((pr * 128 + (koff) * 2) ^ ((pr & 7) << 4))) = pk;       \
  }

#define WGEN16(A0, A1, A2, A3, ktl, buf)                               \
  {                                                                    \
    WGEN4(A0, ktl, pk16 + 0, buf);                                     \
    WGEN4(A1, ktl, pk16 + 4, buf);                                     \
    WGEN4(A2, ktl, pk16 + 8, buf);                                     \
    WGEN4(A3, ktl, pk16 + 12, buf);                                    \
  }

#define LOADADJ16(A0, A1, A2, A3, ktl)                                 \
  {                                                                    \
    const int4v* ap = (const int4v*)(adjp + (size_t)(ktl) * BK);       \
    A0 = __builtin_nontemporal_load(ap);                               \
    A1 = __builtin_nontemporal_load(ap + 1);                           \
    A2 = __builtin_nontemporal_load(ap + 2);                           \
    A3 = __builtin_nontemporal_load(ap + 3);                           \
  }

#define LDA(cur, mr, kk)                                                        \
  __builtin_bit_cast(bf16x8,                                                    \
    *(const ushort8_t*)(sAb + (cur) * 16384 +                                   \
      ((((mr) * 16 + fr) * 128 + (kk) * 64 + fq * 16) ^ ((fr & 7) << 4))))

#define MSTEP(cur, BS)                                                 \
  {                                                                    \
    _Pragma("unroll")                                                  \
    for (int mr = 0; mr < 8; ++mr) {                                   \
      bf16x8 a0 = LDA(cur, mr, 0), a1 = LDA(cur, mr, 1);               \
      acc[mr][0] = MF(a0, BS.b[0][0], acc[mr][0]);                     \
      acc[mr][0] = MF(a1, BS.b[0][1], acc[mr][0]);                     \
      acc[mr][1] = MF(a0, BS.b[1][0], acc[mr][1]);                     \
      acc[mr][1] = MF(a1, BS.b[1][1], acc[mr][1]);                     \
    }                                                                  \
  }

__global__ __launch_bounds__(1024) void k_attn(const int* __restrict__ adj,
                                               const unsigned short* __restrict__ WhF,
                                               const float* __restrict__ src,
                                               const float* __restrict__ dstv,
                                               const unsigned* __restrict__ Dup,
                                               unsigned short* __restrict__ Pb16,
                                               float* __restrict__ Lsum) {
  __shared__ unsigned short sA[2][ROWS][BK];  // 32 KB dbuf, XOR-swizzled rows
  __shared__ float sD[KQ];                    // 8 KB: this quarter's dstv
  char* sAb = (char*)&sA[0][0][0];
  const int tid = threadIdx.x;
  const int lane = tid & 63;
  const int wave = tid >> 6;      // 0..7 consumers, 8..15 producers
  const int qtr = blockIdx.x & 3;
  const int rg = blockIdx.x >> 2;
  const int r0 = rg * ROWS;
  const int ph0 = rg & (NT4 - 1);
  const int kbase = qtr * KQ;
  const float D = funkey(*Dup);

  *(float2*)&sD[tid * 2] = *(const float2*)(dstv + kbase + tid * 2);
  __syncthreads();

  // ---------- producer state (waves 8..15): 4 threads per row ----------
  const int ptid = tid - 512;
  const int pr = ptid >> 2;
  const int pk16 = (ptid & 3) * 16;
  const float s_r = src[r0 + pr];
  const float c_r = lrelu(s_r + D);
  const int* adjp = adj + (size_t)(r0 + pr) * NN + kbase + pk16;
  float lsum = 0.f;

  // ---------- consumer state (waves 0..7): wave tile 128x32 ----------
  const int fr = lane & 15;
  const int fq = lane >> 4;
  const unsigned short* bfw =
      WhF + ((size_t)(qtr * NT4) * 8 + wave) * 2048 + lane * 8;
  f32x4 acc[8][2];
#pragma unroll
  for (int mr = 0; mr < 8; ++mr) {
    acc[mr][0] = (f32x4){0.f, 0.f, 0.f, 0.f};
    acc[mr][1] = (f32x4){0.f, 0.f, 0.f, 0.f};
  }
  Bset B0, B1;
  int4v aA0, aA1, aA2, aA3;
  int4v aB0, aB1, aB2, aB3;

  // ---------- prologue ----------
  if (wave >= 8) {
    int4v d0, d1, d2, d3;
    {
      const int4v* ap = (const int4v*)(adjp + (size_t)TI(0) * BK);
      d0 = ap[0]; d1 = ap[1]; d2 = ap[2]; d3 = ap[3];
    }
    WGEN16(d0, d1, d2, d3, TI(0), 0);
    LOADADJ16(aB0, aB1, aB2, aB3, TI(1));
    LOADADJ16(aA0, aA1, aA2, aA3, TI(2));
  } else {
    LOADB(B0, TI(0));
    LOADB(B1, TI(1));
  }
  BAR();

  // ---------- main loop ----------
  if (wave < 8) {
#pragma unroll 1
    for (int p = 0; p < NT4; p += 2) {
      { MSTEP(0, B0); LOADB(B0, TI(p + 2)); BAR(); }
      { MSTEP(1, B1); LOADB(B1, TI(p + 3)); BAR(); }
    }
    // store bf16 partial accumulators
#pragma unroll
    for (int mr = 0; mr < 8; ++mr) {
#pragma unroll
      for (int r = 0; r < 4; ++r) {
        const int row = mr * 16 + fq * 4 + r;
#pragma unroll
        for (int nc = 0; nc < 2; ++nc) {
          const int col = wave * 32 + nc * 16 + fr;
          Pb16[(size_t)(qtr * NN + r0 + row) * KOUT + col] = f2bf(acc[mr][nc][r]);
        }
      }
    }
  } else {
#pragma unroll 1
    for (int p = 0; p < NT4; p += 2) {
      {
        WGEN16(aB0, aB1, aB2, aB3, TI(p + 1), 1);
        LOADADJ16(aB0, aB1, aB2, aB3, TI(p + 3));
        BAR();
      }
      {
        if (p + 2 < NT4) { WGEN16(aA0, aA1, aA2, aA3, TI(p + 2), 0); }
        LOADADJ16(aA0, aA1, aA2, aA3, TI(p + 4));
        BAR();
      }
    }
    lsum += __shfl_xor(lsum, 1, 4);
    lsum += __shfl_xor(lsum, 2, 4);
    if ((ptid & 3) == 0) Lsum[qtr * NN + r0 + pr] = lsum;
  }
}

// ---------------- k_comb: out = elu(sum(P)/sum(L)) -----------------------
__global__ __launch_bounds__(256) void k_comb(const unsigned short* __restrict__ Pb16,
                                              const float* __restrict__ Lsum,
                                              float* __restrict__ out) {
  const int t = threadIdx.x;
  const int row = blockIdx.x * 4 + (t >> 6);
  const int col = (t & 63) * 4;
  const float l = Lsum[row] + Lsum[NN + row] + Lsum[2 * NN + row] + Lsum[3 * NN + row];
  float s0 = 0.f, s1 = 0.f, s2 = 0.f, s3 = 0.f;
#pragma unroll
  for (int q = 0; q < 4; ++q) {
    ushort4_t p = *(const ushort4_t*)(Pb16 + (size_t)(q * NN + row) * KOUT + col);
    s0 += bf2f(p[0]);
    s1 += bf2f(p[1]);
    s2 += bf2f(p[2]);
    s3 += bf2f(p[3]);
  }
  float4 v;
  v.x = s0 / l;
  v.y = s1 / l;
  v.z = s2 / l;
  v.w = s3 / l;
  v.x = v.x > 0.f ? v.x : __expf(v.x) - 1.f;
  v.y = v.y > 0.f ? v.y : __expf(v.y) - 1.f;
  v.z = v.z > 0.f ? v.z : __expf(v.z) - 1.f;
  v.w = v.w > 0.f ? v.w : __expf(v.w) - 1.f;
  *(float4*)(out + (size_t)row * KOUT + col) = v;
}

extern "C" void kernel_launch(void* const* d_in, const int* in_sizes, int n_in,
                              void* d_out, int out_size, void* d_ws, size_t ws_size,
                              hipStream_t stream) {
  const float* h = (const float*)d_in[0];
  const int* adj = (const int*)d_in[1];
  const float* W = (const float*)d_in[2];
  const float* a1 = (const float*)d_in[3];
  const float* a2 = (const float*)d_in[4];
  float* out = (float*)d_out;

  unsigned short* WhF = (unsigned short*)d_ws;            // 4 MB (fragment order)
  float* src = (float*)(WhF + (size_t)NN * KOUT);         // 32 KB
  float* dstv = src + NN;                                 // 32 KB
  unsigned* Dup = (unsigned*)(dstv + NN);                 // pad 16
  unsigned short* Pb16 = (unsigned short*)(Dup + 16);     // 16 MB bf16 partials
  float* Lsum = (float*)(Pb16 + (size_t)4 * NN * KOUT);   // 128 KB
  unsigned short* Wb = (unsigned short*)(Lsum + 4 * NN);  // 256 KB frag W
  float* Wa1 = (float*)(Wb + (size_t)KIN * KOUT);         // 2 KB
  float* Wa2 = Wa1 + KIN;                                 // 2 KB

  hipLaunchKernelGGL(k_wp, dim3(66), dim3(256), 0, stream, W, a1, a2, Wb, Wa1, Wa2, Dup);
  hipLaunchKernelGGL(k_wh2, dim3(NN / 64), dim3(512), 0, stream,
                     h, Wb, Wa1, Wa2, WhF, src, dstv, Dup);
  hipLaunchKernelGGL(k_attn, dim3(256), dim3(1024), 0, stream,
                     adj, WhF, src, dstv, Dup, Pb16, Lsum);
  hipLaunchKernelGGL(k_comb, dim3(NN / 4), dim3(256), 0, stream, Pb16, Lsum, out);
}